// Round 3
// baseline (267.281 us; speedup 1.0000x reference)
//
#include <hip/hip_runtime.h>

// out[n,i,j] = sum_k x[n,i,k] * w[i,j,k] + b[i,j]   (N=128, D=512)
// One block per i; j-chunks of 16 rows at FULL K. W streamed as contiguous
// 32KB chunks with 2-deep register prefetch; raw s_barrier (NO vmcnt drain)
// + single barrier per chunk => HBM pipe never empties. X in registers.

#define Nn 128
#define Dd 512
#define CHUNK 16
#define NCHUNK (Dd / CHUNK)   // 32

typedef __attribute__((ext_vector_type(8))) short bf16x8;   // MFMA A/B fragment
typedef __attribute__((ext_vector_type(4))) short bf16x4;   // 8B LDS write
typedef __attribute__((ext_vector_type(4))) float f32x4;    // MFMA C/D fragment

__device__ __forceinline__ short f2bf(float f) {
    unsigned u = __builtin_bit_cast(unsigned, f);
    u += 0x7FFFu + ((u >> 16) & 1u);      // round-to-nearest-even
    return (short)(u >> 16);
}

__global__ __launch_bounds__(512, 4)
void linear3d_kernel(const float* __restrict__ x,
                     const float* __restrict__ w,
                     const float* __restrict__ b,
                     float* __restrict__ out) {
    const int i    = blockIdx.x;
    const int tid  = threadIdx.x;
    const int lane = tid & 63;
    const int wid  = tid >> 6;            // 8 waves; wave owns n rows [wid*16, wid*16+16)

    __shared__ short lds[2 * CHUNK * Dd]; // 32 KB: double-buffered W chunk

    const float* xi = x + (size_t)i * Dd;             // x[n,i,k] = xi[n*Dd*Dd + k]
    const float* wi = w + (size_t)i * Dd * Dd;        // w[i,j,k] = wi[j*Dd + k]

    // ---- issue W chunk 0 and 1 loads up front
    float4 wA[4], wB[4];
    #pragma unroll
    for (int p = 0; p < 4; ++p)
        wA[p] = *(const float4*)(wi + (size_t)(tid + p * 512) * 4);
    #pragma unroll
    for (int p = 0; p < 4; ++p)
        wB[p] = *(const float4*)(wi + (size_t)(CHUNK * Dd) + (size_t)(tid + p * 512) * 4);

    // ---- stage X into per-wave register fragments via LDS, 4 rounds of 32 rows
    bf16x8 xf[16];
    #pragma unroll 4
    for (int r = 0; r < 4; ++r) {
        __syncthreads();
        #pragma unroll
        for (int p = 0; p < 8; ++p) {
            int idx4 = tid + p * 512;     // 32 rows x 128 float4
            int row  = idx4 >> 7;
            int c4   = idx4 & 127;
            float4 v = *(const float4*)(xi + (size_t)(r * 32 + row) * (Dd * Dd) + c4 * 4);
            bf16x4 h = { f2bf(v.x), f2bf(v.y), f2bf(v.z), f2bf(v.w) };
            int byte = row * 1024 + c4 * 8;
            byte ^= (row & 7) << 4;       // T2 XOR swizzle
            *(bf16x4*)((char*)lds + byte) = h;
        }
        __syncthreads();
        if ((wid >> 1) == r) {
            int row = (wid & 1) * 16 + (lane & 15);
            #pragma unroll
            for (int s = 0; s < 16; ++s) {
                int byte = row * 1024 + s * 64 + (lane >> 4) * 16;
                byte ^= (row & 7) << 4;
                xf[s] = *(const bf16x8*)((const char*)lds + byte);
            }
        }
    }
    __syncthreads();                      // staging reads done before W0 convert

    // ---- convert W0 (wA) -> buf0
    #pragma unroll
    for (int p = 0; p < 4; ++p) {
        int idx4 = tid + p * 512;         // 16 rows x 128 float4
        int row  = idx4 >> 7;
        int c4   = idx4 & 127;
        bf16x4 h = { f2bf(wA[p].x), f2bf(wA[p].y), f2bf(wA[p].z), f2bf(wA[p].w) };
        int byte = row * 1024 + c4 * 8;
        byte ^= (row & 7) << 4;
        *(bf16x4*)((char*)lds + byte) = h;
    }
    __syncthreads();

    const int nb = wid * 16;
    float* outbase = out + (size_t)i * Dd;
    float bias_cur = b[i * Dd + (lane & 15)];

    // Per chunk: [issue W(c+2) -> WISS] [compute c from buf(c&1)] [store out]
    //            [convert W(c+1) from WCONV -> buf((c+1)&1)] [lgkm0; s_barrier]
    // Single barrier per chunk is sufficient: compute(c) and convert(c) touch
    // disjoint buffers; any write is >=1 barrier after the reads it clobbers.
    // No vmcnt(0) anywhere in the loop -> >=4 W loads always in flight.
#define ITER(c, WISS, WCONV)  do {                                             \
    if ((c) + 2 < NCHUNK) {                                                    \
        const float* src = wi + (size_t)((c) + 2) * (CHUNK * Dd);              \
        _Pragma("unroll")                                                      \
        for (int p = 0; p < 4; ++p)                                            \
            WISS[p] = *(const float4*)(src + (size_t)(tid + p * 512) * 4);     \
    }                                                                          \
    float bias_next = bias_cur;                                                \
    if ((c) + 1 < NCHUNK) bias_next = b[i * Dd + ((c) + 1) * CHUNK + (lane & 15)]; \
    {                                                                          \
        const char* buf = (const char*)lds + (((c) & 1) * (CHUNK * Dd * 2));   \
        f32x4 acc = {0.f, 0.f, 0.f, 0.f};                                      \
        _Pragma("unroll")                                                      \
        for (int s = 0; s < 16; ++s) {                                         \
            int row  = lane & 15;                                              \
            int byte = row * 1024 + s * 64 + (lane >> 4) * 16;                 \
            byte ^= (row & 7) << 4;                                            \
            bf16x8 wf = *(const bf16x8*)(buf + byte);                          \
            acc = __builtin_amdgcn_mfma_f32_16x16x32_bf16(xf[s], wf, acc, 0, 0, 0); \
        }                                                                      \
        _Pragma("unroll")                                                      \
        for (int r = 0; r < 4; ++r) {                                          \
            int n = nb + (lane >> 4) * 4 + r;                                  \
            outbase[(size_t)n * (Dd * Dd) + (c) * CHUNK + (lane & 15)] = acc[r] + bias_cur; \
        }                                                                      \
    }                                                                          \
    if ((c) + 1 < NCHUNK) {                                                    \
        char* dst = (char*)lds + ((((c) + 1) & 1) * (CHUNK * Dd * 2));         \
        _Pragma("unroll")                                                      \
        for (int p = 0; p < 4; ++p) {                                          \
            int idx4 = tid + p * 512;                                          \
            int row  = idx4 >> 7;                                              \
            int c4   = idx4 & 127;                                             \
            bf16x4 h = { f2bf(WCONV[p].x), f2bf(WCONV[p].y), f2bf(WCONV[p].z), f2bf(WCONV[p].w) }; \
            int byte = row * 1024 + c4 * 8;                                    \
            byte ^= (row & 7) << 4;                                            \
            *(bf16x4*)(dst + byte) = h;                                        \
        }                                                                      \
    }                                                                          \
    bias_cur = bias_next;                                                      \
    asm volatile("s_waitcnt lgkmcnt(0)" ::: "memory");                         \
    __builtin_amdgcn_s_barrier();                                              \
    asm volatile("" ::: "memory");                                             \
} while (0)

    for (int c = 0; c < NCHUNK; c += 2) {
        ITER(c,     wA, wB);   // even: issue into wA, convert from wB
        ITER(c + 1, wB, wA);   // odd:  issue into wB, convert from wA
    }
#undef ITER
}

extern "C" void kernel_launch(void* const* d_in, const int* in_sizes, int n_in,
                              void* d_out, int out_size, void* d_ws, size_t ws_size,
                              hipStream_t stream) {
    const float* x = (const float*)d_in[0];
    const float* w = (const float*)d_in[1];
    const float* b = (const float*)d_in[2];
    float* out = (float*)d_out;
    linear3d_kernel<<<dim3(Dd), dim3(512), 0, stream>>>(x, w, b, out);
}

// Round 4
// 184.837 us; speedup vs baseline: 1.4460x; 1.4460x over previous
//
#include <hip/hip_runtime.h>

// out[n,i,j] = sum_k x[n,i,k] * w[i,j,k] + b[i,j]   (N=128, D=512)
// One block per i; j-chunks of 16 at full K. W streamed via global_load_lds
// (f32, zero staging VGPRs), converted once to swizzled bf16 in LDS, then
// fragment-read by all 8 waves. Counted vmcnt(4), no vmcnt(0) in loop.

#define Dd 512
#define CHUNK 16
#define NCHUNK 32

typedef __attribute__((ext_vector_type(8))) short bf16x8;
typedef __attribute__((ext_vector_type(4))) short bf16x4;
typedef __attribute__((ext_vector_type(4))) float f32x4;

__device__ __forceinline__ short f2bf(float f) {
    unsigned u = __builtin_bit_cast(unsigned, f);
    u += 0x7FFFu + ((u >> 16) & 1u);      // RNE
    return (short)(u >> 16);
}

__device__ __forceinline__ void glds16(const float* g, float* l) {
    __builtin_amdgcn_global_load_lds(
        (const __attribute__((address_space(1))) void*)g,
        (__attribute__((address_space(3))) void*)l, 16, 0, 0);
}

__global__ __launch_bounds__(512, 4)
void linear3d_kernel(const float* __restrict__ x,
                     const float* __restrict__ w,
                     const float* __restrict__ b,
                     float* __restrict__ out) {
    const int i    = blockIdx.x;
    const int tid  = threadIdx.x;
    const int lane = tid & 63;
    const int wid  = tid >> 6;            // 8 waves; wave owns n rows [wid*16, +16)

    __shared__ float f32s[CHUNK * Dd];    // 32 KB f32 W chunk (glds target)
    __shared__ short b16[2][CHUNK * Dd];  // 2 x 16 KB swizzled bf16 W chunk
    __shared__ float ldsb[Dd];            // bias row

    const float* xi = x + (size_t)i * Dd;             // x[n,i,k] = xi[n*Dd*Dd + k]
    const float* wi = w + (size_t)i * Dd * Dd;        // w[i,j,k] = wi[j*Dd + k]

    ldsb[tid] = b[i * Dd + tid];

    // ---- issue W chunk 0 -> f32s (linear: wave-uniform dst + lane*16B)
    #pragma unroll
    for (int q = 0; q < 4; ++q)
        glds16(wi + (size_t)(wid * 256 + q * 64 + lane) * 4,
               &f32s[(wid * 256 + q * 64) * 4]);

    // ---- stage X -> per-wave bf16 fragments, using b16 area (32KB) as scratch
    short* xstage = &b16[0][0];
    bf16x8 xf[16];
    #pragma unroll 4
    for (int r = 0; r < 4; ++r) {
        __syncthreads();
        #pragma unroll
        for (int p = 0; p < 8; ++p) {
            int idx4 = tid + p * 512;     // 32 rows x 128 float4
            int row  = idx4 >> 7, c4 = idx4 & 127;
            float4 v = *(const float4*)(xi + (size_t)(r * 32 + row) * (Dd * Dd) + c4 * 4);
            bf16x4 h = { f2bf(v.x), f2bf(v.y), f2bf(v.z), f2bf(v.w) };
            int byte = row * 1024 + c4 * 8;
            byte ^= (row & 7) << 4;       // T2 XOR swizzle
            *(bf16x4*)((char*)xstage + byte) = h;
        }
        __syncthreads();
        if ((wid >> 1) == r) {
            int row = (wid & 1) * 16 + (lane & 15);
            #pragma unroll
            for (int s = 0; s < 16; ++s) {
                int byte = row * 1024 + s * 64 + (lane >> 4) * 16;
                byte ^= (row & 7) << 4;
                xf[s] = *(const bf16x8*)((const char*)xstage + byte);
            }
        }
    }
    __syncthreads();   // staging reads done; also drains glds(0) (vmcnt 0)

    // ---- convert chunk 0: f32s -> b16[0] (each element once)
    #pragma unroll
    for (int p = 0; p < 4; ++p) {
        int idx4 = tid + p * 512;         // 16 rows x 128 float4
        int row = idx4 >> 7, cu = idx4 & 127;
        float4 v = *(const float4*)(f32s + idx4 * 4);
        bf16x4 h = { f2bf(v.x), f2bf(v.y), f2bf(v.z), f2bf(v.w) };
        int byte = row * 1024 + cu * 8;
        byte ^= (row & 7) << 4;
        *(bf16x4*)((char*)&b16[0][0] + byte) = h;
    }
    asm volatile("s_waitcnt lgkmcnt(0)" ::: "memory");
    __builtin_amdgcn_s_barrier();

    // ---- issue W chunk 1 -> f32s
    #pragma unroll
    for (int q = 0; q < 4; ++q)
        glds16(wi + (size_t)(CHUNK * Dd) + (size_t)(wid * 256 + q * 64 + lane) * 4,
               &f32s[(wid * 256 + q * 64) * 4]);

    const int row16 = lane & 15;
    const int nb = wid * 16;
    float* outbase = out + (size_t)i * Dd;

    for (int c = 0; c < NCHUNK; ++c) {
        // ---- compute(c) from b16[c&1]
        const char* buf = (const char*)&b16[c & 1][0];
        f32x4 acc = {0.f, 0.f, 0.f, 0.f};
        #pragma unroll
        for (int s = 0; s < 16; ++s) {
            int byte = row16 * 1024 + s * 64 + (lane >> 4) * 16;
            byte ^= (row16 & 7) << 4;
            bf16x8 wf = *(const bf16x8*)(buf + byte);
            acc = __builtin_amdgcn_mfma_f32_16x16x32_bf16(xf[s], wf, acc, 0, 0, 0);
        }
        float bias = ldsb[c * 16 + row16];
        #pragma unroll
        for (int r = 0; r < 4; ++r) {
            int n = nb + (lane >> 4) * 4 + r;
            outbase[(size_t)n * (Dd * Dd) + c * CHUNK + row16] = acc[r] + bias;
        }

        if (c + 1 < NCHUNK) {
            // glds(c+1) is 8-deep in this wave's vmem queue; the only newer ops
            // are the 4 stores above -> vmcnt(4) guarantees its LDS data landed.
            // vmcnt BEFORE the barrier: after the barrier, ALL waves' glds done.
            asm volatile("s_waitcnt lgkmcnt(0) vmcnt(4)" ::: "memory");
            __builtin_amdgcn_s_barrier();

            // ---- convert(c+1): f32s -> b16[(c+1)&1]
            char* dstb = (char*)&b16[(c + 1) & 1][0];
            #pragma unroll
            for (int p = 0; p < 4; ++p) {
                int idx4 = tid + p * 512;
                int row = idx4 >> 7, cu = idx4 & 127;
                float4 v = *(const float4*)(f32s + idx4 * 4);
                bf16x4 h = { f2bf(v.x), f2bf(v.y), f2bf(v.z), f2bf(v.w) };
                int byte = row * 1024 + cu * 8;
                byte ^= (row & 7) << 4;
                *(bf16x4*)(dstb + byte) = h;
            }
            // convert reads/writes secured, then barrier; then f32s is reusable
            asm volatile("s_waitcnt lgkmcnt(0)" ::: "memory");
            __builtin_amdgcn_s_barrier();

            // ---- issue glds(c+2) -> f32s (pipe never empty; no vmcnt(0) ever)
            if (c + 2 < NCHUNK) {
                const float* src = wi + (size_t)(c + 2) * (CHUNK * Dd);
                #pragma unroll
                for (int q = 0; q < 4; ++q)
                    glds16(src + (size_t)(wid * 256 + q * 64 + lane) * 4,
                           &f32s[(wid * 256 + q * 64) * 4]);
            }
        }
    }
}

extern "C" void kernel_launch(void* const* d_in, const int* in_sizes, int n_in,
                              void* d_out, int out_size, void* d_ws, size_t ws_size,
                              hipStream_t stream) {
    const float* x = (const float*)d_in[0];
    const float* w = (const float*)d_in[1];
    const float* b = (const float*)d_in[2];
    float* out = (float*)d_out;
    linear3d_kernel<<<dim3(Dd), dim3(512), 0, stream>>>(x, w, b, out);
}